// Round 13
// baseline (538.863 us; speedup 1.0000x reference)
//
#include <hip/hip_runtime.h>
#include <hip/hip_bf16.h>

// GraphSAGE 3-layer, N=100000, E=1.6M, dims 256->256->128->1.
// R23: revert R22's slice-major experiment (regressed: L2 thrash + lost
// ILP; 102 vs <=93us). Base = R21 (482us). Change: gemm_l1_fill GEMM tile
// 128x64 -> 256x64 (A-LDS 32KB + B 16KB = 48KB, 3 blocks/CU). Each wave
// owns 64 rows: acc[4][8], 64 MFMA per barrier pair (was 32), B-frags
// reused across 4 row-tiles. R21 counters: 282 TF, MfmaUtil 11% =>
// barrier-drain-bound; bigger tile amortizes it. Grid 7824 = 8*978
// bijective XCD swizzle, 1 gemm : 4 fill blocks. No numerics change:
// absmax must stay exactly 0.005859375.

typedef __attribute__((ext_vector_type(8))) short short8;
typedef __attribute__((ext_vector_type(4))) float f32x4;

__device__ __forceinline__ unsigned short f2b(float f) {
    __hip_bfloat16 h = __float2bfloat16(f);
    return *reinterpret_cast<unsigned short*>(&h);
}
__device__ __forceinline__ float b2f(unsigned short u) {
    union { unsigned int i; float f; } v; v.i = ((unsigned int)u) << 16; return v.f;
}
// fp8 e4m3 (OCP on gfx950) via hardware cvt
__device__ __forceinline__ unsigned char f2q(float f) {
    unsigned int p = __builtin_amdgcn_cvt_pk_fp8_f32(f, f, 0u, false);
    return (unsigned char)(p & 0xffu);
}

__device__ __forceinline__ void gload_lds16(const unsigned short* g, unsigned short* l) {
    __builtin_amdgcn_global_load_lds(
        (const __attribute__((address_space(1))) unsigned int*)(const void*)g,
        (__attribute__((address_space(3))) unsigned int*)(void*)l,
        16, 0, 0);
}

// accumulate 8 fp8 bytes (uint2) into s[0..7] with hardware decode
__device__ __forceinline__ void acc_fp8x8(const uint2 v, float* s) {
    s[0] += __builtin_amdgcn_cvt_f32_fp8(v.x, 0);
    s[1] += __builtin_amdgcn_cvt_f32_fp8(v.x, 1);
    s[2] += __builtin_amdgcn_cvt_f32_fp8(v.x, 2);
    s[3] += __builtin_amdgcn_cvt_f32_fp8(v.x, 3);
    s[4] += __builtin_amdgcn_cvt_f32_fp8(v.y, 0);
    s[5] += __builtin_amdgcn_cvt_f32_fp8(v.y, 1);
    s[6] += __builtin_amdgcn_cvt_f32_fp8(v.y, 2);
    s[7] += __builtin_amdgcn_cvt_f32_fp8(v.y, 3);
}

// ---- fused prep: (convert_x + 64 edges) | prep_w x4 ----------------------
__global__ __launch_bounds__(256) void prep_fused(
    const float* __restrict__ x, unsigned short* __restrict__ xb,
    const float* __restrict__ Wl1, const float* __restrict__ Wr1,
    const float* __restrict__ Wl2, const float* __restrict__ Wr2,
    unsigned short* __restrict__ Wl1s, unsigned short* __restrict__ Wr1s,
    unsigned short* __restrict__ Wl2s, unsigned short* __restrict__ Wr2s,
    const int* __restrict__ dst, int* __restrict__ deg,
    unsigned short* __restrict__ rank, int E)
{
    const int b = blockIdx.x;
    const int tid = threadIdx.x;
    if (b < 25000) {
        const int i = b * 256 + tid;
        float4 v = *(const float4*)(x + (size_t)i * 4);
        ushort4 o;
        o.x = f2b(v.x); o.y = f2b(v.y); o.z = f2b(v.z); o.w = f2b(v.w);
        *(ushort4*)(xb + (size_t)i * 4) = o;
        if (tid < 64) {
            const int e = b * 64 + tid;
            if (e < E) rank[e] = (unsigned short)atomicAdd(&deg[dst[e]], 1);
        }
    } else {
        const float* W; unsigned short* O; int base, hs;
        if (b < 25256)      { W = Wl1; O = Wl1s; base = b - 25000; hs = 8; }
        else if (b < 25512) { W = Wr1; O = Wr1s; base = b - 25256; hs = 8; }
        else if (b < 25640) { W = Wl2; O = Wl2s; base = b - 25512; hs = 7; }
        else                { W = Wr2; O = Wr2s; base = b - 25640; hs = 7; }
        const int i = base * 256 + tid;
        const int k = i >> hs;
        const int h = i & ((1 << hs) - 1);
        O[((size_t)(((k >> 3) << hs) + h) << 3) + (k & 7)] = f2b(W[i]);
    }
}

// ---- scan ----------------------------------------------------------------
__global__ __launch_bounds__(256) void scan_phaseA(int* __restrict__ a,
                                                   int* __restrict__ blockSums, int n) {
    __shared__ int sh[256];
    const int tid = threadIdx.x;
    const int base = blockIdx.x * 1024 + tid * 4;
    int v[4];
    #pragma unroll
    for (int i = 0; i < 4; ++i) v[i] = (base + i < n) ? a[base + i] : 0;
    int tsum = v[0] + v[1] + v[2] + v[3];
    sh[tid] = tsum;
    __syncthreads();
    for (int off = 1; off < 256; off <<= 1) {
        int t = (tid >= off) ? sh[tid - off] : 0;
        __syncthreads();
        sh[tid] += t;
        __syncthreads();
    }
    int run = sh[tid] - tsum;
    #pragma unroll
    for (int i = 0; i < 4; ++i) {
        if (base + i < n) a[base + i] = run;
        run += v[i];
    }
    if (tid == 255) blockSums[blockIdx.x] = sh[255];
}

__global__ __launch_bounds__(256) void scan_phaseB(int* __restrict__ bs, int nb) {
    __shared__ int sh[256];
    const int tid = threadIdx.x;
    int v = (tid < nb) ? bs[tid] : 0;
    sh[tid] = v;
    __syncthreads();
    for (int off = 1; off < 256; off <<= 1) {
        int t = (tid >= off) ? sh[tid - off] : 0;
        __syncthreads();
        sh[tid] += t;
        __syncthreads();
    }
    if (tid < nb) bs[tid] = sh[tid] - v;
}

__global__ __launch_bounds__(256) void scan_phaseC(int* __restrict__ a,
                                                   const int* __restrict__ bs, int n) {
    const int base = blockIdx.x * 1024 + threadIdx.x * 4;
    const int add = bs[blockIdx.x];
    #pragma unroll
    for (int i = 0; i < 4; ++i)
        if (base + i < n) a[base + i] += add;
}

// ---- fused L1 GEMM (256x64 LDS-staged, fp8 Tout) + atomic-free fill ------
__global__ __launch_bounds__(256) void gemm_l1_fill(
    const unsigned short* __restrict__ Xb,
    const unsigned short* __restrict__ Wsw_l,
    const unsigned short* __restrict__ Wsw_r,
    const float* __restrict__ bias,
    unsigned char* __restrict__ Tout,          // fp8 e4m3 [N][256]
    unsigned short* __restrict__ Abase,
    int M,
    const int* __restrict__ src, const int* __restrict__ dst,
    const int* __restrict__ starts, const unsigned short* __restrict__ rank,
    int* __restrict__ csr, int E)
{
    // bijective XCD swizzle: grid = 7824 = 8 * 978
    const int bid = (blockIdx.x & 7) * 978 + (blockIdx.x >> 3);
    const int grp = bid / 5;
    const int rem = bid - grp * 5;
    const int tid = threadIdx.x;

    if (rem != 0 || grp >= 1564) {         // fill_csr part: no atomics
        const int e = (grp * 4 + rem - 1) * 256 + tid;
        if (rem != 0 && e < E) csr[starts[dst[e]] + (int)rank[e]] = src[e];
        return;
    }

    // ---- gemm: 256 rows x 64 cols x {Wl,Wr}, K=256, BK=64 ---------------
    // LDS: A [row 256][chunk 8]x16B = 32KB at smem[0..16384)
    //      B [mat 2][ko 8][col 64]x16B = 16KB at smem[16384..24576) (ushorts)
    __shared__ unsigned short smem[24576];

    const int wid = tid >> 6;
    const int lane = tid & 63;
    const int quad = lane >> 4;
    const int l15 = lane & 15;
    const int col0 = (grp & 3) << 6;
    const int m0 = (grp >> 2) * 256;

    const unsigned short* aSrc[8];
    unsigned int aOfs[8];
    #pragma unroll
    for (int i = 0; i < 8; ++i) {
        const int slot = i * 256 + tid;
        const int r = slot >> 3, cs = slot & 7;
        const int cg = cs ^ (r & 7);       // content swizzle on global source
        aSrc[i] = Xb + ((size_t)(m0 + r) << 8) + (cg << 3);
        aOfs[i] = (unsigned)((i * 256 + wid * 64) * 8);
    }
    const unsigned short* bSrc[4];
    unsigned int bOfs[4];
    #pragma unroll
    for (int i = 0; i < 4; ++i) {
        const int slot = i * 256 + tid;
        const int mat = slot >> 9, ko = (slot >> 6) & 7, col = slot & 63;
        const unsigned short* Wm = mat ? Wsw_r : Wsw_l;
        bSrc[i] = Wm + (((size_t)ko * 256 + col0 + col) << 3);
        bOfs[i] = (unsigned)(16384 + (i * 256 + wid * 64) * 8);
    }

    const f32x4 zero = {0.f, 0.f, 0.f, 0.f};
    f32x4 acc[4][8];
    #pragma unroll
    for (int mt = 0; mt < 4; ++mt)
        #pragma unroll
        for (int nt = 0; nt < 8; ++nt) acc[mt][nt] = zero;

    for (int ks = 0; ks < 4; ++ks) {
        #pragma unroll
        for (int i = 0; i < 8; ++i)
            gload_lds16(aSrc[i] + ks * 64, smem + aOfs[i]);
        #pragma unroll
        for (int i = 0; i < 4; ++i)
            gload_lds16(bSrc[i] + ks * 16384, smem + bOfs[i]);
        __syncthreads();

        #pragma unroll
        for (int k32 = 0; k32 < 2; ++k32) {
            short8 af[4], bf[8];
            #pragma unroll
            for (int mt = 0; mt < 4; ++mt) {
                const int row = wid * 64 + mt * 16 + l15;
                const int c = (k32 * 4 + quad) ^ (row & 7);
                af[mt] = *(const short8*)(smem + ((row << 3) + c) * 8);
            }
            #pragma unroll
            for (int nt = 0; nt < 4; ++nt) {
                const int colL = nt * 16 + l15;
                const int ko = k32 * 4 + quad;
                bf[nt]     = *(const short8*)(smem + 16384 + ((ko << 6) + colL) * 8);
                bf[nt + 4] = *(const short8*)(smem + 16384 + (512 + (ko << 6) + colL) * 8);
            }
            #pragma unroll
            for (int mt = 0; mt < 4; ++mt)
                #pragma unroll
                for (int nt = 0; nt < 8; ++nt)
                    acc[mt][nt] = __builtin_amdgcn_mfma_f32_16x16x32_bf16(
                        af[mt], bf[nt], acc[mt][nt], 0, 0, 0);
        }
        __syncthreads();
    }

    #pragma unroll
    for (int nt = 0; nt < 4; ++nt) {
        const int colg = col0 + nt * 16 + l15;
        const float bb = bias[colg];
        #pragma unroll
        for (int mt = 0; mt < 4; ++mt) {
            const int gmb = m0 + wid * 64 + mt * 16 + quad * 4;
            #pragma unroll
            for (int r = 0; r < 4; ++r) {
                if (gmb + r < M) {
                    Tout [(size_t)(gmb + r) * 256 + colg] = f2q(acc[mt][nt][r]);
                    Abase[(size_t)(gmb + r) * 256 + colg] = f2b(acc[mt][nt + 4][r] + bb);
                }
            }
        }
    }
}

// ---- layer-2 aggregation: half-wave/node, fp8 rows (256B), shfl idx ------
__global__ __launch_bounds__(256) void agg256_b(
    const int* __restrict__ endoff, const int* __restrict__ csr,
    const unsigned char* __restrict__ T,       // fp8 e4m3 [N][256]
    const unsigned short* __restrict__ Abase, unsigned short* __restrict__ Xout,
    int N, int E)
{
    const int node = (int)((blockIdx.x * 256 + threadIdx.x) >> 5);
    const int lane = threadIdx.x & 31;
    const int hsel = threadIdx.x & 32;     // half-of-wave64 selector for shfl
    if (node >= N) return;
    const int beg = endoff[node];
    const int end = (node + 1 < N) ? endoff[node + 1] : E;
    float s[8] = {0.f, 0.f, 0.f, 0.f, 0.f, 0.f, 0.f, 0.f};

    for (int base = beg; base < end; base += 32) {
        const int il = base + lane;
        const int vidx = csr[il < E ? il : (E - 1)];   // 32 indices / 1 load
        const int cnt = (end - base < 32) ? (end - base) : 32;
        int u = 0;
        for (; u + 16 <= cnt; u += 16) {
            uint2 v[16];
            #pragma unroll
            for (int k = 0; k < 16; ++k) {
                const int r = __shfl(vidx, (u + k) | hsel, 64);
                v[k] = *(const uint2*)(T + ((size_t)r << 8) + (lane << 3));
            }
            #pragma unroll
            for (int k = 0; k < 16; ++k) acc_fp8x8(v[k], s);
        }
        if (u + 8 <= cnt) {
            uint2 v[8];
            #pragma unroll
            for (int k = 0; k < 8; ++k) {
                const int r = __shfl(vidx, (u + k) | hsel, 64);
                v[k] = *(const uint2*)(T + ((size_t)r << 8) + (lane << 3));
            }
            #pragma unroll
            for (int k = 0; k < 8; ++k) acc_fp8x8(v[k], s);
            u += 8;
        }
        for (; u < cnt; ++u) {
            const int r = __shfl(vidx, u | hsel, 64);
            const uint2 v = *(const uint2*)(T + ((size_t)r << 8) + (lane << 3));
            acc_fp8x8(v, s);
        }
    }

    const float w = 1.0f / fmaxf((float)(end - beg), 1.0f);
    const short8 bu = *(const short8*)(Abase + ((size_t)node << 8) + (lane << 3));
    short8 o;
    #pragma unroll
    for (int j = 0; j < 8; ++j)
        o[j] = (short)f2b(fmaxf(b2f((unsigned short)bu[j]) + s[j] * w, 0.f));
    *(short8*)(Xout + ((size_t)node << 8) + (lane << 3)) = o;
}

// ---- standalone L2 GEMM (H=128, K=256), fp8 Tout -------------------------
__global__ __launch_bounds__(256) void gemm_bf16(
    const unsigned short* __restrict__ Xb,
    const unsigned short* __restrict__ Wsw_l,
    const unsigned short* __restrict__ Wsw_r,
    const float* __restrict__ bias,
    unsigned char* __restrict__ Tout,          // fp8 e4m3 [N][128]
    unsigned short* __restrict__ Abase,
    int M, int H)
{
    const int tid = threadIdx.x;
    const int wid = tid >> 6;
    const int lane = tid & 63;
    const int quad = lane >> 4;
    const int l15 = lane & 15;

    const int col0 = blockIdx.x << 6;
    const int m0 = blockIdx.y * 128 + wid * 32;

    const unsigned short* aptr[2];
    #pragma unroll
    for (int mt = 0; mt < 2; ++mt) {
        int r = m0 + mt * 16 + l15;
        if (r > M - 1) r = M - 1;
        aptr[mt] = Xb + ((size_t)r << 8) + (quad << 3);
    }
    const unsigned short* bptr[8];
    #pragma unroll
    for (int nt = 0; nt < 4; ++nt) {
        const int col = col0 + nt * 16 + l15;
        bptr[nt]     = Wsw_l + (((size_t)quad * H + col) << 3);
        bptr[nt + 4] = Wsw_r + (((size_t)quad * H + col) << 3);
    }

    const f32x4 zero = {0.f, 0.f, 0.f, 0.f};
    f32x4 acc[2][8];
    #pragma unroll
    for (int mt = 0; mt < 2; ++mt)
        #pragma unroll
        for (int nt = 0; nt < 8; ++nt) acc[mt][nt] = zero;

    #pragma unroll 2
    for (int ks = 0; ks < 8; ++ks) {
        short8 af[2], bf[8];
        #pragma unroll
        for (int mt = 0; mt < 2; ++mt)
            af[mt] = *(const short8*)(aptr[mt] + ks * 32);
        #pragma unroll
        for (int nt = 0; nt < 8; ++nt)
            bf[nt] = *(const short8*)(bptr[nt] + (size_t)ks * 32 * H);
        #pragma unroll
        for (int mt = 0; mt < 2; ++mt)
            #pragma unroll
            for (int nt = 0; nt < 8; ++nt)
                acc[mt][nt] = __builtin_amdgcn_mfma_f32_16x16x32_bf16(
                    af[mt], bf[nt], acc[mt][nt], 0, 0, 0);
    }

    #pragma unroll
    for (int nt = 0; nt < 4; ++nt) {
        const int colg = col0 + nt * 16 + l15;
        const float bb = bias[colg];
        #pragma unroll
        for (int mt = 0; mt < 2; ++mt) {
            const int gmb = m0 + mt * 16 + quad * 4;
            #pragma unroll
            for (int r = 0; r < 4; ++r) {
                if (gmb + r < M) {
                    Tout [(size_t)(gmb + r) * H + colg] = f2q(acc[mt][nt][r]);
                    Abase[(size_t)(gmb + r) * H + colg] = f2b(acc[mt][nt + 4][r] + bb);
                }
            }
        }
    }
}

// ---- fused layer-3: agg128 (fp8 rows) + gemv, shfl-broadcast idx ---------
__global__ __launch_bounds__(256) void agg_gemv3(
    const int* __restrict__ endoff, const int* __restrict__ csr,
    const unsigned char* __restrict__ T,       // fp8 e4m3 [N][128]
    const unsigned short* __restrict__ Ab,
    const float* __restrict__ Wl, const float* __restrict__ Wr,
    const float* __restrict__ b,
    float* __restrict__ t3, float* __restrict__ out, int N, int E)
{
    const int node = (int)((blockIdx.x * 256 + threadIdx.x) >> 5);
    const int lane = threadIdx.x & 31;
    const int hsel = threadIdx.x & 32;
    if (node >= N) return;
    const int beg = endoff[node];
    const int end = (node + 1 < N) ? endoff[node + 1] : E;
    float s0 = 0.f, s1 = 0.f, s2 = 0.f, s3 = 0.f;

    for (int base = beg; base < end; base += 32) {
        const int il = base + lane;
        const int vidx = csr[il < E ? il : (E - 1)];
        const int cnt = (end - base < 32) ? (end - base) : 32;
        int u = 0;
        for (; u + 16 <= cnt; u += 16) {
            unsigned int v[16];
            #pragma unroll
            for (int k = 0; k < 16; ++k) {
                const int r = __shfl(vidx, (u + k) | hsel, 64);
                v[k] = *(const unsigned int*)(T + ((size_t)r << 7) + (lane << 2));
            }
            #pragma unroll
            for (int k = 0; k < 16; ++k) {
                s0 += __builtin_amdgcn_cvt_f32_fp8(v[k], 0);
                s1 += __builtin_amdgcn_cvt_f32_fp8(v[k], 1);
                s2 += __builtin_amdgcn_cvt_f32_fp8(v[k], 2);
                s3 += __builtin_amdgcn_cvt_f32_fp8(v[k], 3);
            }
        }
        if (u + 8 <= cnt) {
            unsigned int v[8];
            #pragma unroll
            for (int k = 0; k < 8; ++k) {
                const int r = __shfl(vidx, (u + k) | hsel, 64);
                v[k] = *(const unsigned int*)(T + ((size_t)r << 7) + (lane << 2));
            }
            #pragma unroll
            for (int k = 0; k < 8; ++k) {
                s0 += __builtin_amdgcn_cvt_f32_fp8(v[k], 0);
                s1 += __builtin_amdgcn_cvt_f32_fp8(v[k], 1);
                s2 += __builtin_amdgcn_cvt_f32_fp8(v[k], 2);
                s3 += __builtin_amdgcn_cvt_f32_fp8(v[k], 3);
            }
            u += 8;
        }
        for (; u < cnt; ++u) {
            const int r = __shfl(vidx, u | hsel, 64);
            const unsigned int v = *(const unsigned int*)(T + ((size_t)r << 7) + (lane << 2));
            s0 += __builtin_amdgcn_cvt_f32_fp8(v, 0);
            s1 += __builtin_amdgcn_cvt_f32_fp8(v, 1);
            s2 += __builtin_amdgcn_cvt_f32_fp8(v, 2);
            s3 += __builtin_amdgcn_cvt_f32_fp8(v, 3);
        }
    }

    const float w = 1.0f / fmaxf((float)(end - beg), 1.0f);
    const ushort4 bu = *(const ushort4*)(Ab + ((size_t)node << 7) + (lane << 2));
    const float h0 = fmaxf(b2f(bu.x) + s0 * w, 0.f);
    const float h1 = fmaxf(b2f(bu.y) + s1 * w, 0.f);
    const float h2 = fmaxf(b2f(bu.z) + s2 * w, 0.f);
    const float h3 = fmaxf(b2f(bu.w) + s3 * w, 0.f);

    const float4 wl = *(const float4*)(Wl + (lane << 2));
    const float4 wr = *(const float4*)(Wr + (lane << 2));
    float dl = h0 * wl.x + h1 * wl.y + h2 * wl.z + h3 * wl.w;
    float dr = h0 * wr.x + h1 * wr.y + h2 * wr.z + h3 * wr.w;
    #pragma unroll
    for (int off = 16; off > 0; off >>= 1) {
        dl += __shfl_down(dl, off, 64);
        dr += __shfl_down(dr, off, 64);
    }
    if (lane == 0) {
        t3[node] = dl;
        out[node] = dr + b[0];
    }
}

__global__ __launch_bounds__(256) void agg1(
    const int* __restrict__ endoff, const int* __restrict__ csr,
    const float* __restrict__ t3, float* __restrict__ out, int N, int E)
{
    const int i = blockIdx.x * blockDim.x + threadIdx.x;
    if (i >= N) return;
    const int beg = endoff[i];
    const int end = (i + 1 < N) ? endoff[i + 1] : E;
    int p = beg;
    float s = 0.f;
    for (; p + 4 <= end; p += 4)
        s += (t3[csr[p]] + t3[csr[p + 1]]) + (t3[csr[p + 2]] + t3[csr[p + 3]]);
    for (; p < end; ++p) s += t3[csr[p]];
    out[i] += s / fmaxf((float)(end - beg), 1.0f);
}

extern "C" void kernel_launch(void* const* d_in, const int* in_sizes, int n_in,
                              void* d_out, int out_size, void* d_ws, size_t ws_size,
                              hipStream_t stream) {
    const float* x   = (const float*)d_in[0];
    const int*   ei  = (const int*)d_in[1];
    const float* Wl1 = (const float*)d_in[2];
    const float* bl1 = (const float*)d_in[3];
    const float* Wr1 = (const float*)d_in[4];
    const float* Wl2 = (const float*)d_in[5];
    const float* bl2 = (const float*)d_in[6];
    const float* Wr2 = (const float*)d_in[7];
    const float* Wl3 = (const float*)d_in[8];
    const float* bl3 = (const float*)d_in[9];
    const float* Wr3 = (const float*)d_in[10];
    float* out = (float*)d_out;

    const int N = in_sizes[0] / 256;   // 100000
    const int E = in_sizes[1] / 2;     // 1600000
    const int* src = ei;
    const int* dst = ei + E;

    // ---- workspace layout, race-free aliasing ----------------------------
    //   prep:       W X1b[0,51.2), rank, deg
    //   L1+fill:    R X1b,rank,starts  W T1b(fp8)[51.2,76.8) A1b[102.4,153.6) csr
    //   agg256_b:   R T1b,A1b,csr      W X2b[0,51.2)          (X1b dead)
    //   gemm_l2:    R X2b              W T2b(fp8)[51.2,64.0) A2b[76.8,102.4)
    //   agg_gemv3:  R T2b,A2b,csr      W t3,out               (X2b dead)
    //   agg1:       R t3,csr           RW out
    char* W = (char*)d_ws;
    const size_t MB512 = (size_t)100000 * 512;   // 51.2MB
    unsigned short* X1b = (unsigned short*)(W);
    unsigned char*  T1b = (unsigned char*)(W + MB512);           // fp8, 25.6MB
    unsigned short* A1b = (unsigned short*)(W + 2 * MB512);
    unsigned short* X2b = (unsigned short*)(W);                  // over dead X1b
    unsigned char*  T2b = (unsigned char*)(W + MB512);           // fp8, over dead T1b
    unsigned short* A2b = (unsigned short*)(W + MB512 + MB512 / 2);
    char* S = W + 3 * MB512;                     // smalls @ 153.6M
    int*   endoff = (int*)(S);
    int*   bsums  = (int*)(S + (size_t)N * 4);
    float* t3     = (float*)(S + (size_t)N * 4 + 1024);
    int*   csr    = (int*)(S + (size_t)N * 8 + 1024);
    unsigned short* Wl1s = (unsigned short*)(S + (size_t)N * 8 + 1024 + (size_t)E * 4);
    unsigned short* Wr1s = Wl1s + 65536;
    unsigned short* Wl2s = Wr1s + 65536;
    unsigned short* Wr2s = Wl2s + 32768;
    unsigned short* rank = Wr2s + 32768;         // ushort[E], +3.2MB

    // ---- prep: fused conversions + interleaved degree count ----
    hipMemsetAsync(endoff, 0, (size_t)N * sizeof(int), stream);
    prep_fused<<<25768, 256, 0, stream>>>(
        x, X1b, Wl1, Wr1, Wl2, Wr2, Wl1s, Wr1s, Wl2s, Wr2s,
        dst, endoff, rank, E);
    const int nScanBlocks = (N + 1023) / 1024;
    scan_phaseA<<<nScanBlocks, 256, 0, stream>>>(endoff, bsums, N);
    scan_phaseB<<<1, 256, 0, stream>>>(bsums, nScanBlocks);
    scan_phaseC<<<nScanBlocks, 256, 0, stream>>>(endoff, bsums, N);

    // ---- Layer 1 GEMM (256x64 tile) fused with atomic-free fill ----
    gemm_l1_fill<<<7824, 256, 0, stream>>>(X1b, Wl1s, Wr1s, bl1, T1b, A1b, N,
                                           src, dst, endoff, rank, csr, E);

    // ---- Layer 2: gather (half-wave/node, fp8 rows) then GEMM ----
    agg256_b<<<(N * 32 + 255) / 256, 256, 0, stream>>>(endoff, csr, T1b, A1b, X2b, N, E);
    gemm_bf16<<<dim3(2, (N + 127) / 128), 256, 0, stream>>>(X2b, Wl2s, Wr2s, bl2,
                                                            T2b, A2b, N, 128);

    // ---- Layer 3: fused agg128 (fp8) + gemv, then final scalar agg ----
    agg_gemv3<<<(N * 32 + 255) / 256, 256, 0, stream>>>(endoff, csr, T2b, A2b,
                                                        Wl3, Wr3, bl3, t3, out, N, E);
    agg1<<<(N + 255) / 256, 256, 0, stream>>>(endoff, csr, t3, out, N, E);
}

// Round 14
// 473.476 us; speedup vs baseline: 1.1381x; 1.1381x over previous
//
#include <hip/hip_runtime.h>
#include <hip/hip_bf16.h>

// GraphSAGE 3-layer, N=100000, E=1.6M, dims 256->256->128->1.
// R24: revert R23's 256x64 tile (occupancy crash 27->10%, 93->148us;
// the mixed gemm+fill block population needs TLP, not per-block MFMA
// density). Base = R21 (482us). Change: packed fp8 decode in both
// gathers - v_cvt_pk_f32_fp8 (2 floats/inst) replaces per-byte
// v_cvt_f32_fp8, halving the ~42us/kernel decode VALU chain (R22
// measured VALUBusy 41% - decode co-limits with the ~3TB/s gather
// wall). Identical hardware conversion values: absmax must stay
// exactly 0.005859375.

typedef __attribute__((ext_vector_type(8))) short short8;
typedef __attribute__((ext_vector_type(4))) float f32x4;
typedef __attribute__((ext_vector_type(2))) float f32x2;

__device__ __forceinline__ unsigned short f2b(float f) {
    __hip_bfloat16 h = __float2bfloat16(f);
    return *reinterpret_cast<unsigned short*>(&h);
}
__device__ __forceinline__ float b2f(unsigned short u) {
    union { unsigned int i; float f; } v; v.i = ((unsigned int)u) << 16; return v.f;
}
// fp8 e4m3 (OCP on gfx950) via hardware cvt
__device__ __forceinline__ unsigned char f2q(float f) {
    unsigned int p = __builtin_amdgcn_cvt_pk_fp8_f32(f, f, 0u, false);
    return (unsigned char)(p & 0xffu);
}

__device__ __forceinline__ void gload_lds16(const unsigned short* g, unsigned short* l) {
    __builtin_amdgcn_global_load_lds(
        (const __attribute__((address_space(1))) unsigned int*)(const void*)g,
        (__attribute__((address_space(3))) unsigned int*)(void*)l,
        16, 0, 0);
}

// accumulate 8 fp8 bytes (uint2) into s[0..7] with packed hardware decode
__device__ __forceinline__ void acc_fp8x8(const uint2 v, float* s) {
    const f32x2 a0 = __builtin_amdgcn_cvt_pk_f32_fp8(v.x, false);
    const f32x2 a1 = __builtin_amdgcn_cvt_pk_f32_fp8(v.x, true);
    const f32x2 b0 = __builtin_amdgcn_cvt_pk_f32_fp8(v.y, false);
    const f32x2 b1 = __builtin_amdgcn_cvt_pk_f32_fp8(v.y, true);
    s[0] += a0[0]; s[1] += a0[1]; s[2] += a1[0]; s[3] += a1[1];
    s[4] += b0[0]; s[5] += b0[1]; s[6] += b1[0]; s[7] += b1[1];
}

// ---- fused prep: (convert_x + 64 edges) | prep_w x4 ----------------------
__global__ __launch_bounds__(256) void prep_fused(
    const float* __restrict__ x, unsigned short* __restrict__ xb,
    const float* __restrict__ Wl1, const float* __restrict__ Wr1,
    const float* __restrict__ Wl2, const float* __restrict__ Wr2,
    unsigned short* __restrict__ Wl1s, unsigned short* __restrict__ Wr1s,
    unsigned short* __restrict__ Wl2s, unsigned short* __restrict__ Wr2s,
    const int* __restrict__ dst, int* __restrict__ deg,
    unsigned short* __restrict__ rank, int E)
{
    const int b = blockIdx.x;
    const int tid = threadIdx.x;
    if (b < 25000) {
        const int i = b * 256 + tid;
        float4 v = *(const float4*)(x + (size_t)i * 4);
        ushort4 o;
        o.x = f2b(v.x); o.y = f2b(v.y); o.z = f2b(v.z); o.w = f2b(v.w);
        *(ushort4*)(xb + (size_t)i * 4) = o;
        if (tid < 64) {
            const int e = b * 64 + tid;
            if (e < E) rank[e] = (unsigned short)atomicAdd(&deg[dst[e]], 1);
        }
    } else {
        const float* W; unsigned short* O; int base, hs;
        if (b < 25256)      { W = Wl1; O = Wl1s; base = b - 25000; hs = 8; }
        else if (b < 25512) { W = Wr1; O = Wr1s; base = b - 25256; hs = 8; }
        else if (b < 25640) { W = Wl2; O = Wl2s; base = b - 25512; hs = 7; }
        else                { W = Wr2; O = Wr2s; base = b - 25640; hs = 7; }
        const int i = base * 256 + tid;
        const int k = i >> hs;
        const int h = i & ((1 << hs) - 1);
        O[((size_t)(((k >> 3) << hs) + h) << 3) + (k & 7)] = f2b(W[i]);
    }
}

// ---- scan ----------------------------------------------------------------
__global__ __launch_bounds__(256) void scan_phaseA(int* __restrict__ a,
                                                   int* __restrict__ blockSums, int n) {
    __shared__ int sh[256];
    const int tid = threadIdx.x;
    const int base = blockIdx.x * 1024 + tid * 4;
    int v[4];
    #pragma unroll
    for (int i = 0; i < 4; ++i) v[i] = (base + i < n) ? a[base + i] : 0;
    int tsum = v[0] + v[1] + v[2] + v[3];
    sh[tid] = tsum;
    __syncthreads();
    for (int off = 1; off < 256; off <<= 1) {
        int t = (tid >= off) ? sh[tid - off] : 0;
        __syncthreads();
        sh[tid] += t;
        __syncthreads();
    }
    int run = sh[tid] - tsum;
    #pragma unroll
    for (int i = 0; i < 4; ++i) {
        if (base + i < n) a[base + i] = run;
        run += v[i];
    }
    if (tid == 255) blockSums[blockIdx.x] = sh[255];
}

__global__ __launch_bounds__(256) void scan_phaseB(int* __restrict__ bs, int nb) {
    __shared__ int sh[256];
    const int tid = threadIdx.x;
    int v = (tid < nb) ? bs[tid] : 0;
    sh[tid] = v;
    __syncthreads();
    for (int off = 1; off < 256; off <<= 1) {
        int t = (tid >= off) ? sh[tid - off] : 0;
        __syncthreads();
        sh[tid] += t;
        __syncthreads();
    }
    if (tid < nb) bs[tid] = sh[tid] - v;
}

__global__ __launch_bounds__(256) void scan_phaseC(int* __restrict__ a,
                                                   const int* __restrict__ bs, int n) {
    const int base = blockIdx.x * 1024 + threadIdx.x * 4;
    const int add = bs[blockIdx.x];
    #pragma unroll
    for (int i = 0; i < 4; ++i)
        if (base + i < n) a[base + i] += add;
}

// ---- fused L1 GEMM (LDS-staged, fp8 Tout) + atomic-free fill_csr ---------
__global__ __launch_bounds__(256) void gemm_l1_fill(
    const unsigned short* __restrict__ Xb,
    const unsigned short* __restrict__ Wsw_l,
    const unsigned short* __restrict__ Wsw_r,
    const float* __restrict__ bias,
    unsigned char* __restrict__ Tout,          // fp8 e4m3 [N][256]
    unsigned short* __restrict__ Abase,
    int M,
    const int* __restrict__ src, const int* __restrict__ dst,
    const int* __restrict__ starts, const unsigned short* __restrict__ rank,
    int* __restrict__ csr, int E)
{
    // bijective XCD swizzle: grid = 9384 = 8 * 1173
    const int bid = (blockIdx.x & 7) * 1173 + (blockIdx.x >> 3);
    const int grp = bid / 3;
    const int rem = bid - grp * 3;
    const int tid = threadIdx.x;

    if (rem != 0) {                        // fill_csr part: no atomics
        const int e = (grp * 2 + rem - 1) * 256 + tid;
        if (e < E) csr[starts[dst[e]] + (int)rank[e]] = src[e];
        return;
    }

    // ---- gemm part: 128 rows x 64 cols x {Wl,Wr}, K=256, BK=64 ----------
    __shared__ unsigned short smem[16384];

    const int wid = tid >> 6;
    const int lane = tid & 63;
    const int quad = lane >> 4;
    const int l15 = lane & 15;
    const int col0 = (grp & 3) << 6;
    const int m0 = (grp >> 2) * 128;

    const unsigned short* aSrc[4];
    unsigned int aOfs[4];
    #pragma unroll
    for (int i = 0; i < 4; ++i) {
        const int slot = i * 256 + tid;
        const int r = slot >> 3, cs = slot & 7;
        const int cg = cs ^ (r & 7);
        aSrc[i] = Xb + ((size_t)(m0 + r) << 8) + (cg << 3);
        aOfs[i] = (unsigned)((i * 256 + wid * 64) * 8);
    }
    const unsigned short* bSrc[4];
    unsigned int bOfs[4];
    #pragma unroll
    for (int i = 0; i < 4; ++i) {
        const int slot = i * 256 + tid;
        const int mat = slot >> 9, ko = (slot >> 6) & 7, col = slot & 63;
        const unsigned short* Wm = mat ? Wsw_r : Wsw_l;
        bSrc[i] = Wm + (((size_t)ko * 256 + col0 + col) << 3);
        bOfs[i] = (unsigned)(8192 + (i * 256 + wid * 64) * 8);
    }

    const f32x4 zero = {0.f, 0.f, 0.f, 0.f};
    f32x4 acc[2][8];
    #pragma unroll
    for (int mt = 0; mt < 2; ++mt)
        #pragma unroll
        for (int nt = 0; nt < 8; ++nt) acc[mt][nt] = zero;

    for (int ks = 0; ks < 4; ++ks) {
        #pragma unroll
        for (int i = 0; i < 4; ++i)
            gload_lds16(aSrc[i] + ks * 64, smem + aOfs[i]);
        #pragma unroll
        for (int i = 0; i < 4; ++i)
            gload_lds16(bSrc[i] + ks * 16384, smem + bOfs[i]);
        __syncthreads();

        #pragma unroll
        for (int k32 = 0; k32 < 2; ++k32) {
            short8 af[2], bf[8];
            #pragma unroll
            for (int mt = 0; mt < 2; ++mt) {
                const int row = wid * 32 + mt * 16 + l15;
                const int c = (k32 * 4 + quad) ^ (row & 7);
                af[mt] = *(const short8*)(smem + ((row << 3) + c) * 8);
            }
            #pragma unroll
            for (int nt = 0; nt < 4; ++nt) {
                const int colL = nt * 16 + l15;
                const int ko = k32 * 4 + quad;
                bf[nt]     = *(const short8*)(smem + 8192 + ((ko << 6) + colL) * 8);
                bf[nt + 4] = *(const short8*)(smem + 8192 + (512 + (ko << 6) + colL) * 8);
            }
            #pragma unroll
            for (int mt = 0; mt < 2; ++mt)
                #pragma unroll
                for (int nt = 0; nt < 8; ++nt)
                    acc[mt][nt] = __builtin_amdgcn_mfma_f32_16x16x32_bf16(
                        af[mt], bf[nt], acc[mt][nt], 0, 0, 0);
        }
        __syncthreads();
    }

    #pragma unroll
    for (int nt = 0; nt < 4; ++nt) {
        const int colg = col0 + nt * 16 + l15;
        const float bb = bias[colg];
        #pragma unroll
        for (int mt = 0; mt < 2; ++mt) {
            const int gmb = m0 + wid * 32 + mt * 16 + quad * 4;
            #pragma unroll
            for (int r = 0; r < 4; ++r) {
                if (gmb + r < M) {
                    Tout [(size_t)(gmb + r) * 256 + colg] = f2q(acc[mt][nt][r]);
                    Abase[(size_t)(gmb + r) * 256 + colg] = f2b(acc[mt][nt + 4][r] + bb);
                }
            }
        }
    }
}

// ---- layer-2 aggregation: half-wave/node, fp8 rows (256B), shfl idx ------
__global__ __launch_bounds__(256) void agg256_b(
    const int* __restrict__ endoff, const int* __restrict__ csr,
    const unsigned char* __restrict__ T,       // fp8 e4m3 [N][256]
    const unsigned short* __restrict__ Abase, unsigned short* __restrict__ Xout,
    int N, int E)
{
    const int node = (int)((blockIdx.x * 256 + threadIdx.x) >> 5);
    const int lane = threadIdx.x & 31;
    const int hsel = threadIdx.x & 32;     // half-of-wave64 selector for shfl
    if (node >= N) return;
    const int beg = endoff[node];
    const int end = (node + 1 < N) ? endoff[node + 1] : E;
    float s[8] = {0.f, 0.f, 0.f, 0.f, 0.f, 0.f, 0.f, 0.f};

    for (int base = beg; base < end; base += 32) {
        const int il = base + lane;
        const int vidx = csr[il < E ? il : (E - 1)];   // 32 indices / 1 load
        const int cnt = (end - base < 32) ? (end - base) : 32;
        int u = 0;
        for (; u + 16 <= cnt; u += 16) {
            uint2 v[16];
            #pragma unroll
            for (int k = 0; k < 16; ++k) {
                const int r = __shfl(vidx, (u + k) | hsel, 64);
                v[k] = *(const uint2*)(T + ((size_t)r << 8) + (lane << 3));
            }
            #pragma unroll
            for (int k = 0; k < 16; ++k) acc_fp8x8(v[k], s);
        }
        if (u + 8 <= cnt) {
            uint2 v[8];
            #pragma unroll
            for (int k = 0; k < 8; ++k) {
                const int r = __shfl(vidx, (u + k) | hsel, 64);
                v[k] = *(const uint2*)(T + ((size_t)r << 8) + (lane << 3));
            }
            #pragma unroll
            for (int k = 0; k < 8; ++k) acc_fp8x8(v[k], s);
            u += 8;
        }
        for (; u < cnt; ++u) {
            const int r = __shfl(vidx, u | hsel, 64);
            const uint2 v = *(const uint2*)(T + ((size_t)r << 8) + (lane << 3));
            acc_fp8x8(v, s);
        }
    }

    const float w = 1.0f / fmaxf((float)(end - beg), 1.0f);
    const short8 bu = *(const short8*)(Abase + ((size_t)node << 8) + (lane << 3));
    short8 o;
    #pragma unroll
    for (int j = 0; j < 8; ++j)
        o[j] = (short)f2b(fmaxf(b2f((unsigned short)bu[j]) + s[j] * w, 0.f));
    *(short8*)(Xout + ((size_t)node << 8) + (lane << 3)) = o;
}

// ---- standalone L2 GEMM (H=128, K=256), fp8 Tout -------------------------
__global__ __launch_bounds__(256) void gemm_bf16(
    const unsigned short* __restrict__ Xb,
    const unsigned short* __restrict__ Wsw_l,
    const unsigned short* __restrict__ Wsw_r,
    const float* __restrict__ bias,
    unsigned char* __restrict__ Tout,          // fp8 e4m3 [N][128]
    unsigned short* __restrict__ Abase,
    int M, int H)
{
    const int tid = threadIdx.x;
    const int wid = tid >> 6;
    const int lane = tid & 63;
    const int quad = lane >> 4;
    const int l15 = lane & 15;

    const int col0 = blockIdx.x << 6;
    const int m0 = blockIdx.y * 128 + wid * 32;

    const unsigned short* aptr[2];
    #pragma unroll
    for (int mt = 0; mt < 2; ++mt) {
        int r = m0 + mt * 16 + l15;
        if (r > M - 1) r = M - 1;
        aptr[mt] = Xb + ((size_t)r << 8) + (quad << 3);
    }
    const unsigned short* bptr[8];
    #pragma unroll
    for (int nt = 0; nt < 4; ++nt) {
        const int col = col0 + nt * 16 + l15;
        bptr[nt]     = Wsw_l + (((size_t)quad * H + col) << 3);
        bptr[nt + 4] = Wsw_r + (((size_t)quad * H + col) << 3);
    }

    const f32x4 zero = {0.f, 0.f, 0.f, 0.f};
    f32x4 acc[2][8];
    #pragma unroll
    for (int mt = 0; mt < 2; ++mt)
        #pragma unroll
        for (int nt = 0; nt < 8; ++nt) acc[mt][nt] = zero;

    #pragma unroll 2
    for (int ks = 0; ks < 8; ++ks) {
        short8 af[2], bf[8];
        #pragma unroll
        for (int mt = 0; mt < 2; ++mt)
            af[mt] = *(const short8*)(aptr[mt] + ks * 32);
        #pragma unroll
        for (int nt = 0; nt < 8; ++nt)
            bf[nt] = *(const short8*)(bptr[nt] + (size_t)ks * 32 * H);
        #pragma unroll
        for (int mt = 0; mt < 2; ++mt)
            #pragma unroll
            for (int nt = 0; nt < 8; ++nt)
                acc[mt][nt] = __builtin_amdgcn_mfma_f32_16x16x32_bf16(
                    af[mt], bf[nt], acc[mt][nt], 0, 0, 0);
    }

    #pragma unroll
    for (int nt = 0; nt < 4; ++nt) {
        const int colg = col0 + nt * 16 + l15;
        const float bb = bias[colg];
        #pragma unroll
        for (int mt = 0; mt < 2; ++mt) {
            const int gmb = m0 + mt * 16 + quad * 4;
            #pragma unroll
            for (int r = 0; r < 4; ++r) {
                if (gmb + r < M) {
                    Tout [(size_t)(gmb + r) * H + colg] = f2q(acc[mt][nt][r]);
                    Abase[(size_t)(gmb + r) * H + colg] = f2b(acc[mt][nt + 4][r] + bb);
                }
            }
        }
    }
}

// ---- fused layer-3: agg128 (fp8 rows) + gemv, shfl-broadcast idx ---------
__global__ __launch_bounds__(256) void agg_gemv3(
    const int* __restrict__ endoff, const int* __restrict__ csr,
    const unsigned char* __restrict__ T,       // fp8 e4m3 [N][128]
    const unsigned short* __restrict__ Ab,
    const float* __restrict__ Wl, const float* __restrict__ Wr,
    const float* __restrict__ b,
    float* __restrict__ t3, float* __restrict__ out, int N, int E)
{
    const int node = (int)((blockIdx.x * 256 + threadIdx.x) >> 5);
    const int lane = threadIdx.x & 31;
    const int hsel = threadIdx.x & 32;
    if (node >= N) return;
    const int beg = endoff[node];
    const int end = (node + 1 < N) ? endoff[node + 1] : E;
    float s0 = 0.f, s1 = 0.f, s2 = 0.f, s3 = 0.f;

    for (int base = beg; base < end; base += 32) {
        const int il = base + lane;
        const int vidx = csr[il < E ? il : (E - 1)];
        const int cnt = (end - base < 32) ? (end - base) : 32;
        int u = 0;
        for (; u + 16 <= cnt; u += 16) {
            unsigned int v[16];
            #pragma unroll
            for (int k = 0; k < 16; ++k) {
                const int r = __shfl(vidx, (u + k) | hsel, 64);
                v[k] = *(const unsigned int*)(T + ((size_t)r << 7) + (lane << 2));
            }
            #pragma unroll
            for (int k = 0; k < 16; ++k) {
                const f32x2 lo = __builtin_amdgcn_cvt_pk_f32_fp8(v[k], false);
                const f32x2 hi = __builtin_amdgcn_cvt_pk_f32_fp8(v[k], true);
                s0 += lo[0]; s1 += lo[1]; s2 += hi[0]; s3 += hi[1];
            }
        }
        if (u + 8 <= cnt) {
            unsigned int v[8];
            #pragma unroll
            for (int k = 0; k < 8; ++k) {
                const int r = __shfl(vidx, (u + k) | hsel, 64);
                v[k] = *(const unsigned int*)(T + ((size_t)r << 7) + (lane << 2));
            }
            #pragma unroll
            for (int k = 0; k < 8; ++k) {
                const f32x2 lo = __builtin_amdgcn_cvt_pk_f32_fp8(v[k], false);
                const f32x2 hi = __builtin_amdgcn_cvt_pk_f32_fp8(v[k], true);
                s0 += lo[0]; s1 += lo[1]; s2 += hi[0]; s3 += hi[1];
            }
            u += 8;
        }
        for (; u < cnt; ++u) {
            const int r = __shfl(vidx, u | hsel, 64);
            const unsigned int v = *(const unsigned int*)(T + ((size_t)r << 7) + (lane << 2));
            const f32x2 lo = __builtin_amdgcn_cvt_pk_f32_fp8(v, false);
            const f32x2 hi = __builtin_amdgcn_cvt_pk_f32_fp8(v, true);
            s0 += lo[0]; s1 += lo[1]; s2 += hi[0]; s3 += hi[1];
        }
    }

    const float w = 1.0f / fmaxf((float)(end - beg), 1.0f);
    const ushort4 bu = *(const ushort4*)(Ab + ((size_t)node << 7) + (lane << 2));
    const float h0 = fmaxf(b2f(bu.x) + s0 * w, 0.f);
    const float h1 = fmaxf(b2f(bu.y) + s1 * w, 0.f);
    const float h2 = fmaxf(b2f(bu.z) + s2 * w, 0.f);
    const float h3 = fmaxf(b2f(bu.w) + s3 * w, 0.f);

    const float4 wl = *(const float4*)(Wl + (lane << 2));
    const float4 wr = *(const float4*)(Wr + (lane << 2));
    float dl = h0 * wl.x + h1 * wl.y + h2 * wl.z + h3 * wl.w;
    float dr = h0 * wr.x + h1 * wr.y + h2 * wr.z + h3 * wr.w;
    #pragma unroll
    for (int off = 16; off > 0; off >>= 1) {
        dl += __shfl_down(dl, off, 64);
        dr += __shfl_down(dr, off, 64);
    }
    if (lane == 0) {
        t3[node] = dl;
        out[node] = dr + b[0];
    }
}

__global__ __launch_bounds__(256) void agg1(
    const int* __restrict__ endoff, const int* __restrict__ csr,
    const float* __restrict__ t3, float* __restrict__ out, int N, int E)
{
    const int i = blockIdx.x * blockDim.x + threadIdx.x;
    if (i >= N) return;
    const int beg = endoff[i];
    const int end = (i + 1 < N) ? endoff[i + 1] : E;
    int p = beg;
    float s = 0.f;
    for (; p + 4 <= end; p += 4)
        s += (t3[csr[p]] + t3[csr[p + 1]]) + (t3[csr[p + 2]] + t3[csr[p + 3]]);
    for (; p < end; ++p) s += t3[csr[p]];
    out[i] += s / fmaxf((float)(end - beg), 1.0f);
}

extern "C" void kernel_launch(void* const* d_in, const int* in_sizes, int n_in,
                              void* d_out, int out_size, void* d_ws, size_t ws_size,
                              hipStream_t stream) {
    const float* x   = (const float*)d_in[0];
    const int*   ei  = (const int*)d_in[1];
    const float* Wl1 = (const float*)d_in[2];
    const float* bl1 = (const float*)d_in[3];
    const float* Wr1 = (const float*)d_in[4];
    const float* Wl2 = (const float*)d_in[5];
    const float* bl2 = (const float*)d_in[6];
    const float* Wr2 = (const float*)d_in[7];
    const float* Wl3 = (const float*)d_in[8];
    const float* bl3 = (const float*)d_in[9];
    const float* Wr3 = (const float*)d_in[10];
    float* out = (float*)d_out;

    const int N = in_sizes[0] / 256;   // 100000
    const int E = in_sizes[1] / 2;     // 1600000
    const int* src = ei;
    const int* dst = ei + E;

    // ---- workspace layout, race-free aliasing ----------------------------
    //   prep:       W X1b[0,51.2), rank, deg
    //   L1+fill:    R X1b,rank,starts  W T1b(fp8)[51.2,76.8) A1b[102.4,153.6) csr
    //   agg256_b:   R T1b,A1b,csr      W X2b[0,51.2)          (X1b dead)
    //   gemm_l2:    R X2b              W T2b(fp8)[51.2,64.0) A2b[76.8,102.4)
    //   agg_gemv3:  R T2b,A2b,csr      W t3,out               (X2b dead)
    //   agg1:       R t3,csr           RW out
    char* W = (char*)d_ws;
    const size_t MB512 = (size_t)100000 * 512;   // 51.2MB
    unsigned short* X1b = (unsigned short*)(W);
    unsigned char*  T1b = (unsigned char*)(W + MB512);           // fp8, 25.6MB
    unsigned short* A1b = (unsigned short*)(W + 2 * MB512);
    unsigned short* X2b = (unsigned short*)(W);                  // over dead X1b
    unsigned char*  T2b = (unsigned char*)(W + MB512);           // fp8, over dead T1b
    unsigned short* A2b = (unsigned short*)(W + MB512 + MB512 / 2);
    char* S = W + 3 * MB512;                     // smalls @ 153.6M
    int*   endoff = (int*)(S);
    int*   bsums  = (int*)(S + (size_t)N * 4);
    float* t3     = (float*)(S + (size_t)N * 4 + 1024);
    int*   csr    = (int*)(S + (size_t)N * 8 + 1024);
    unsigned short* Wl1s = (unsigned short*)(S + (size_t)N * 8 + 1024 + (size_t)E * 4);
    unsigned short* Wr1s = Wl1s + 65536;
    unsigned short* Wl2s = Wr1s + 65536;
    unsigned short* Wr2s = Wl2s + 32768;
    unsigned short* rank = Wr2s + 32768;         // ushort[E], +3.2MB

    // ---- prep: fused conversions + interleaved degree count ----
    hipMemsetAsync(endoff, 0, (size_t)N * sizeof(int), stream);
    prep_fused<<<25768, 256, 0, stream>>>(
        x, X1b, Wl1, Wr1, Wl2, Wr2, Wl1s, Wr1s, Wl2s, Wr2s,
        dst, endoff, rank, E);
    const int nScanBlocks = (N + 1023) / 1024;
    scan_phaseA<<<nScanBlocks, 256, 0, stream>>>(endoff, bsums, N);
    scan_phaseB<<<1, 256, 0, stream>>>(bsums, nScanBlocks);
    scan_phaseC<<<nScanBlocks, 256, 0, stream>>>(endoff, bsums, N);

    // ---- Layer 1 GEMM (LDS-staged, fp8 T) fused with atomic-free fill ----
    gemm_l1_fill<<<3128 * 3, 256, 0, stream>>>(X1b, Wl1s, Wr1s, bl1, T1b, A1b, N,
                                               src, dst, endoff, rank, csr, E);

    // ---- Layer 2: gather (half-wave/node, fp8 rows) then GEMM ----
    agg256_b<<<(N * 32 + 255) / 256, 256, 0, stream>>>(endoff, csr, T1b, A1b, X2b, N, E);
    gemm_bf16<<<dim3(2, (N + 127) / 128), 256, 0, stream>>>(X2b, Wl2s, Wr2s, bl2,
                                                            T2b, A2b, N, 128);

    // ---- Layer 3: fused agg128 (fp8) + gemv, then final scalar agg ----
    agg_gemv3<<<(N * 32 + 255) / 256, 256, 0, stream>>>(endoff, csr, T2b, A2b,
                                                        Wl3, Wr3, bl3, t3, out, N, E);
    agg1<<<(N + 255) / 256, 256, 0, stream>>>(endoff, csr, t3, out, N, E);
}

// Round 16
// 471.223 us; speedup vs baseline: 1.1435x; 1.0048x over previous
//
#include <hip/hip_runtime.h>
#include <hip/hip_bf16.h>

// GraphSAGE 3-layer, N=100000, E=1.6M, dims 256->256->128->1.
// R26: revert of R25 (skip-path fp8 A1b/A2b blew the accuracy budget:
// absmax 0.0166 > threshold 0.0096 - self-path quantization is not
// degree-attenuated). Back to R24 verbatim = best passing kernel
// (473.5us, absmax 0.005859375): fp8 T1b/T2b gathered tensors,
// atomic-free rank fill, LDS-staged 128x64 L1 GEMM + XCD swizzle,
// shfl-broadcast gathers with packed v_cvt_pk_f32_fp8 decode,
// interleaved prep. All remaining kernels pinned by experimentally
// adjudicated floors (csr scatter sectors, XCD replication, BW+atomics).

typedef __attribute__((ext_vector_type(8))) short short8;
typedef __attribute__((ext_vector_type(4))) float f32x4;
typedef __attribute__((ext_vector_type(2))) float f32x2;

__device__ __forceinline__ unsigned short f2b(float f) {
    __hip_bfloat16 h = __float2bfloat16(f);
    return *reinterpret_cast<unsigned short*>(&h);
}
__device__ __forceinline__ float b2f(unsigned short u) {
    union { unsigned int i; float f; } v; v.i = ((unsigned int)u) << 16; return v.f;
}
// fp8 e4m3 (OCP on gfx950) via hardware cvt
__device__ __forceinline__ unsigned char f2q(float f) {
    unsigned int p = __builtin_amdgcn_cvt_pk_fp8_f32(f, f, 0u, false);
    return (unsigned char)(p & 0xffu);
}

__device__ __forceinline__ void gload_lds16(const unsigned short* g, unsigned short* l) {
    __builtin_amdgcn_global_load_lds(
        (const __attribute__((address_space(1))) unsigned int*)(const void*)g,
        (__attribute__((address_space(3))) unsigned int*)(void*)l,
        16, 0, 0);
}

// accumulate 8 fp8 bytes (uint2) into s[0..7] with packed hardware decode
__device__ __forceinline__ void acc_fp8x8(const uint2 v, float* s) {
    const f32x2 a0 = __builtin_amdgcn_cvt_pk_f32_fp8(v.x, false);
    const f32x2 a1 = __builtin_amdgcn_cvt_pk_f32_fp8(v.x, true);
    const f32x2 b0 = __builtin_amdgcn_cvt_pk_f32_fp8(v.y, false);
    const f32x2 b1 = __builtin_amdgcn_cvt_pk_f32_fp8(v.y, true);
    s[0] += a0[0]; s[1] += a0[1]; s[2] += a1[0]; s[3] += a1[1];
    s[4] += b0[0]; s[5] += b0[1]; s[6] += b1[0]; s[7] += b1[1];
}

// ---- fused prep: (convert_x + 64 edges) | prep_w x4 ----------------------
__global__ __launch_bounds__(256) void prep_fused(
    const float* __restrict__ x, unsigned short* __restrict__ xb,
    const float* __restrict__ Wl1, const float* __restrict__ Wr1,
    const float* __restrict__ Wl2, const float* __restrict__ Wr2,
    unsigned short* __restrict__ Wl1s, unsigned short* __restrict__ Wr1s,
    unsigned short* __restrict__ Wl2s, unsigned short* __restrict__ Wr2s,
    const int* __restrict__ dst, int* __restrict__ deg,
    unsigned short* __restrict__ rank, int E)
{
    const int b = blockIdx.x;
    const int tid = threadIdx.x;
    if (b < 25000) {
        const int i = b * 256 + tid;
        float4 v = *(const float4*)(x + (size_t)i * 4);
        ushort4 o;
        o.x = f2b(v.x); o.y = f2b(v.y); o.z = f2b(v.z); o.w = f2b(v.w);
        *(ushort4*)(xb + (size_t)i * 4) = o;
        if (tid < 64) {
            const int e = b * 64 + tid;
            if (e < E) rank[e] = (unsigned short)atomicAdd(&deg[dst[e]], 1);
        }
    } else {
        const float* W; unsigned short* O; int base, hs;
        if (b < 25256)      { W = Wl1; O = Wl1s; base = b - 25000; hs = 8; }
        else if (b < 25512) { W = Wr1; O = Wr1s; base = b - 25256; hs = 8; }
        else if (b < 25640) { W = Wl2; O = Wl2s; base = b - 25512; hs = 7; }
        else                { W = Wr2; O = Wr2s; base = b - 25640; hs = 7; }
        const int i = base * 256 + tid;
        const int k = i >> hs;
        const int h = i & ((1 << hs) - 1);
        O[((size_t)(((k >> 3) << hs) + h) << 3) + (k & 7)] = f2b(W[i]);
    }
}

// ---- scan ----------------------------------------------------------------
__global__ __launch_bounds__(256) void scan_phaseA(int* __restrict__ a,
                                                   int* __restrict__ blockSums, int n) {
    __shared__ int sh[256];
    const int tid = threadIdx.x;
    const int base = blockIdx.x * 1024 + tid * 4;
    int v[4];
    #pragma unroll
    for (int i = 0; i < 4; ++i) v[i] = (base + i < n) ? a[base + i] : 0;
    int tsum = v[0] + v[1] + v[2] + v[3];
    sh[tid] = tsum;
    __syncthreads();
    for (int off = 1; off < 256; off <<= 1) {
        int t = (tid >= off) ? sh[tid - off] : 0;
        __syncthreads();
        sh[tid] += t;
        __syncthreads();
    }
    int run = sh[tid] - tsum;
    #pragma unroll
    for (int i = 0; i < 4; ++i) {
        if (base + i < n) a[base + i] = run;
        run += v[i];
    }
    if (tid == 255) blockSums[blockIdx.x] = sh[255];
}

__global__ __launch_bounds__(256) void scan_phaseB(int* __restrict__ bs, int nb) {
    __shared__ int sh[256];
    const int tid = threadIdx.x;
    int v = (tid < nb) ? bs[tid] : 0;
    sh[tid] = v;
    __syncthreads();
    for (int off = 1; off < 256; off <<= 1) {
        int t = (tid >= off) ? sh[tid - off] : 0;
        __syncthreads();
        sh[tid] += t;
        __syncthreads();
    }
    if (tid < nb) bs[tid] = sh[tid] - v;
}

__global__ __launch_bounds__(256) void scan_phaseC(int* __restrict__ a,
                                                   const int* __restrict__ bs, int n) {
    const int base = blockIdx.x * 1024 + threadIdx.x * 4;
    const int add = bs[blockIdx.x];
    #pragma unroll
    for (int i = 0; i < 4; ++i)
        if (base + i < n) a[base + i] += add;
}

// ---- fused L1 GEMM (LDS-staged, fp8 Tout) + atomic-free fill_csr ---------
__global__ __launch_bounds__(256) void gemm_l1_fill(
    const unsigned short* __restrict__ Xb,
    const unsigned short* __restrict__ Wsw_l,
    const unsigned short* __restrict__ Wsw_r,
    const float* __restrict__ bias,
    unsigned char* __restrict__ Tout,          // fp8 e4m3 [N][256]
    unsigned short* __restrict__ Abase,
    int M,
    const int* __restrict__ src, const int* __restrict__ dst,
    const int* __restrict__ starts, const unsigned short* __restrict__ rank,
    int* __restrict__ csr, int E)
{
    // bijective XCD swizzle: grid = 9384 = 8 * 1173
    const int bid = (blockIdx.x & 7) * 1173 + (blockIdx.x >> 3);
    const int grp = bid / 3;
    const int rem = bid - grp * 3;
    const int tid = threadIdx.x;

    if (rem != 0) {                        // fill_csr part: no atomics
        const int e = (grp * 2 + rem - 1) * 256 + tid;
        if (e < E) csr[starts[dst[e]] + (int)rank[e]] = src[e];
        return;
    }

    // ---- gemm part: 128 rows x 64 cols x {Wl,Wr}, K=256, BK=64 ----------
    __shared__ unsigned short smem[16384];

    const int wid = tid >> 6;
    const int lane = tid & 63;
    const int quad = lane >> 4;
    const int l15 = lane & 15;
    const int col0 = (grp & 3) << 6;
    const int m0 = (grp >> 2) * 128;

    const unsigned short* aSrc[4];
    unsigned int aOfs[4];
    #pragma unroll
    for (int i = 0; i < 4; ++i) {
        const int slot = i * 256 + tid;
        const int r = slot >> 3, cs = slot & 7;
        const int cg = cs ^ (r & 7);
        aSrc[i] = Xb + ((size_t)(m0 + r) << 8) + (cg << 3);
        aOfs[i] = (unsigned)((i * 256 + wid * 64) * 8);
    }
    const unsigned short* bSrc[4];
    unsigned int bOfs[4];
    #pragma unroll
    for (int i = 0; i < 4; ++i) {
        const int slot = i * 256 + tid;
        const int mat = slot >> 9, ko = (slot >> 6) & 7, col = slot & 63;
        const unsigned short* Wm = mat ? Wsw_r : Wsw_l;
        bSrc[i] = Wm + (((size_t)ko * 256 + col0 + col) << 3);
        bOfs[i] = (unsigned)(8192 + (i * 256 + wid * 64) * 8);
    }

    const f32x4 zero = {0.f, 0.f, 0.f, 0.f};
    f32x4 acc[2][8];
    #pragma unroll
    for (int mt = 0; mt < 2; ++mt)
        #pragma unroll
        for (int nt = 0; nt < 8; ++nt) acc[mt][nt] = zero;

    for (int ks = 0; ks < 4; ++ks) {
        #pragma unroll
        for (int i = 0; i < 4; ++i)
            gload_lds16(aSrc[i] + ks * 64, smem + aOfs[i]);
        #pragma unroll
        for (int i = 0; i < 4; ++i)
            gload_lds16(bSrc[i] + ks * 16384, smem + bOfs[i]);
        __syncthreads();

        #pragma unroll
        for (int k32 = 0; k32 < 2; ++k32) {
            short8 af[2], bf[8];
            #pragma unroll
            for (int mt = 0; mt < 2; ++mt) {
                const int row = wid * 32 + mt * 16 + l15;
                const int c = (k32 * 4 + quad) ^ (row & 7);
                af[mt] = *(const short8*)(smem + ((row << 3) + c) * 8);
            }
            #pragma unroll
            for (int nt = 0; nt < 4; ++nt) {
                const int colL = nt * 16 + l15;
                const int ko = k32 * 4 + quad;
                bf[nt]     = *(const short8*)(smem + 8192 + ((ko << 6) + colL) * 8);
                bf[nt + 4] = *(const short8*)(smem + 8192 + (512 + (ko << 6) + colL) * 8);
            }
            #pragma unroll
            for (int mt = 0; mt < 2; ++mt)
                #pragma unroll
                for (int nt = 0; nt < 8; ++nt)
                    acc[mt][nt] = __builtin_amdgcn_mfma_f32_16x16x32_bf16(
                        af[mt], bf[nt], acc[mt][nt], 0, 0, 0);
        }
        __syncthreads();
    }

    #pragma unroll
    for (int nt = 0; nt < 4; ++nt) {
        const int colg = col0 + nt * 16 + l15;
        const float bb = bias[colg];
        #pragma unroll
        for (int mt = 0; mt < 2; ++mt) {
            const int gmb = m0 + wid * 32 + mt * 16 + quad * 4;
            #pragma unroll
            for (int r = 0; r < 4; ++r) {
                if (gmb + r < M) {
                    Tout [(size_t)(gmb + r) * 256 + colg] = f2q(acc[mt][nt][r]);
                    Abase[(size_t)(gmb + r) * 256 + colg] = f2b(acc[mt][nt + 4][r] + bb);
                }
            }
        }
    }
}

// ---- layer-2 aggregation: half-wave/node, fp8 rows (256B), shfl idx ------
__global__ __launch_bounds__(256) void agg256_b(
    const int* __restrict__ endoff, const int* __restrict__ csr,
    const unsigned char* __restrict__ T,       // fp8 e4m3 [N][256]
    const unsigned short* __restrict__ Abase, unsigned short* __restrict__ Xout,
    int N, int E)
{
    const int node = (int)((blockIdx.x * 256 + threadIdx.x) >> 5);
    const int lane = threadIdx.x & 31;
    const int hsel = threadIdx.x & 32;     // half-of-wave64 selector for shfl
    if (node >= N) return;
    const int beg = endoff[node];
    const int end = (node + 1 < N) ? endoff[node + 1] : E;
    float s[8] = {0.f, 0.f, 0.f, 0.f, 0.f, 0.f, 0.f, 0.f};

    for (int base = beg; base < end; base += 32) {
        const int il = base + lane;
        const int vidx = csr[il < E ? il : (E - 1)];   // 32 indices / 1 load
        const int cnt = (end - base < 32) ? (end - base) : 32;
        int u = 0;
        for (; u + 16 <= cnt; u += 16) {
            uint2 v[16];
            #pragma unroll
            for (int k = 0; k < 16; ++k) {
                const int r = __shfl(vidx, (u + k) | hsel, 64);
                v[k] = *(const uint2*)(T + ((size_t)r << 8) + (lane << 3));
            }
            #pragma unroll
            for (int k = 0; k < 16; ++k) acc_fp8x8(v[k], s);
        }
        if (u + 8 <= cnt) {
            uint2 v[8];
            #pragma unroll
            for (int k = 0; k < 8; ++k) {
                const int r = __shfl(vidx, (u + k) | hsel, 64);
                v[k] = *(const uint2*)(T + ((size_t)r << 8) + (lane << 3));
            }
            #pragma unroll
            for (int k = 0; k < 8; ++k) acc_fp8x8(v[k], s);
            u += 8;
        }
        for (; u < cnt; ++u) {
            const int r = __shfl(vidx, u | hsel, 64);
            const uint2 v = *(const uint2*)(T + ((size_t)r << 8) + (lane << 3));
            acc_fp8x8(v, s);
        }
    }

    const float w = 1.0f / fmaxf((float)(end - beg), 1.0f);
    const short8 bu = *(const short8*)(Abase + ((size_t)node << 8) + (lane << 3));
    short8 o;
    #pragma unroll
    for (int j = 0; j < 8; ++j)
        o[j] = (short)f2b(fmaxf(b2f((unsigned short)bu[j]) + s[j] * w, 0.f));
    *(short8*)(Xout + ((size_t)node << 8) + (lane << 3)) = o;
}

// ---- standalone L2 GEMM (H=128, K=256), fp8 Tout -------------------------
__global__ __launch_bounds__(256) void gemm_bf16(
    const unsigned short* __restrict__ Xb,
    const unsigned short* __restrict__ Wsw_l,
    const unsigned short* __restrict__ Wsw_r,
    const float* __restrict__ bias,
    unsigned char* __restrict__ Tout,          // fp8 e4m3 [N][128]
    unsigned short* __restrict__ Abase,
    int M, int H)
{
    const int tid = threadIdx.x;
    const int wid = tid >> 6;
    const int lane = tid & 63;
    const int quad = lane >> 4;
    const int l15 = lane & 15;

    const int col0 = blockIdx.x << 6;
    const int m0 = blockIdx.y * 128 + wid * 32;

    const unsigned short* aptr[2];
    #pragma unroll
    for (int mt = 0; mt < 2; ++mt) {
        int r = m0 + mt * 16 + l15;
        if (r > M - 1) r = M - 1;
        aptr[mt] = Xb + ((size_t)r << 8) + (quad << 3);
    }
    const unsigned short* bptr[8];
    #pragma unroll
    for (int nt = 0; nt < 4; ++nt) {
        const int col = col0 + nt * 16 + l15;
        bptr[nt]     = Wsw_l + (((size_t)quad * H + col) << 3);
        bptr[nt + 4] = Wsw_r + (((size_t)quad * H + col) << 3);
    }

    const f32x4 zero = {0.f, 0.f, 0.f, 0.f};
    f32x4 acc[2][8];
    #pragma unroll
    for (int mt = 0; mt < 2; ++mt)
        #pragma unroll
        for (int nt = 0; nt < 8; ++nt) acc[mt][nt] = zero;

    #pragma unroll 2
    for (int ks = 0; ks < 8; ++ks) {
        short8 af[2], bf[8];
        #pragma unroll
        for (int mt = 0; mt < 2; ++mt)
            af[mt] = *(const short8*)(aptr[mt] + ks * 32);
        #pragma unroll
        for (int nt = 0; nt < 8; ++nt)
            bf[nt] = *(const short8*)(bptr[nt] + (size_t)ks * 32 * H);
        #pragma unroll
        for (int mt = 0; mt < 2; ++mt)
            #pragma unroll
            for (int nt = 0; nt < 8; ++nt)
                acc[mt][nt] = __builtin_amdgcn_mfma_f32_16x16x32_bf16(
                    af[mt], bf[nt], acc[mt][nt], 0, 0, 0);
    }

    #pragma unroll
    for (int nt = 0; nt < 4; ++nt) {
        const int colg = col0 + nt * 16 + l15;
        const float bb = bias[colg];
        #pragma unroll
        for (int mt = 0; mt < 2; ++mt) {
            const int gmb = m0 + mt * 16 + quad * 4;
            #pragma unroll
            for (int r = 0; r < 4; ++r) {
                if (gmb + r < M) {
                    Tout [(size_t)(gmb + r) * H + colg] = f2q(acc[mt][nt][r]);
                    Abase[(size_t)(gmb + r) * H + colg] = f2b(acc[mt][nt + 4][r] + bb);
                }
            }
        }
    }
}

// ---- fused layer-3: agg128 (fp8 rows) + gemv, shfl-broadcast idx ---------
__global__ __launch_bounds__(256) void agg_gemv3(
    const int* __restrict__ endoff, const int* __restrict__ csr,
    const unsigned char* __restrict__ T,       // fp8 e4m3 [N][128]
    const unsigned short* __restrict__ Ab,
    const float* __restrict__ Wl, const float* __restrict__ Wr,
    const float* __restrict__ b,
    float* __restrict__ t3, float* __restrict__ out, int N, int E)
{
    const int node = (int)((blockIdx.x * 256 + threadIdx.x) >> 5);
    const int lane = threadIdx.x & 31;
    const int hsel = threadIdx.x & 32;
    if (node >= N) return;
    const int beg = endoff[node];
    const int end = (node + 1 < N) ? endoff[node + 1] : E;
    float s0 = 0.f, s1 = 0.f, s2 = 0.f, s3 = 0.f;

    for (int base = beg; base < end; base += 32) {
        const int il = base + lane;
        const int vidx = csr[il < E ? il : (E - 1)];
        const int cnt = (end - base < 32) ? (end - base) : 32;
        int u = 0;
        for (; u + 16 <= cnt; u += 16) {
            unsigned int v[16];
            #pragma unroll
            for (int k = 0; k < 16; ++k) {
                const int r = __shfl(vidx, (u + k) | hsel, 64);
                v[k] = *(const unsigned int*)(T + ((size_t)r << 7) + (lane << 2));
            }
            #pragma unroll
            for (int k = 0; k < 16; ++k) {
                const f32x2 lo = __builtin_amdgcn_cvt_pk_f32_fp8(v[k], false);
                const f32x2 hi = __builtin_amdgcn_cvt_pk_f32_fp8(v[k], true);
                s0 += lo[0]; s1 += lo[1]; s2 += hi[0]; s3 += hi[1];
            }
        }
        if (u + 8 <= cnt) {
            unsigned int v[8];
            #pragma unroll
            for (int k = 0; k < 8; ++k) {
                const int r = __shfl(vidx, (u + k) | hsel, 64);
                v[k] = *(const unsigned int*)(T + ((size_t)r << 7) + (lane << 2));
            }
            #pragma unroll
            for (int k = 0; k < 8; ++k) {
                const f32x2 lo = __builtin_amdgcn_cvt_pk_f32_fp8(v[k], false);
                const f32x2 hi = __builtin_amdgcn_cvt_pk_f32_fp8(v[k], true);
                s0 += lo[0]; s1 += lo[1]; s2 += hi[0]; s3 += hi[1];
            }
            u += 8;
        }
        for (; u < cnt; ++u) {
            const int r = __shfl(vidx, u | hsel, 64);
            const unsigned int v = *(const unsigned int*)(T + ((size_t)r << 7) + (lane << 2));
            const f32x2 lo = __builtin_amdgcn_cvt_pk_f32_fp8(v, false);
            const f32x2 hi = __builtin_amdgcn_cvt_pk_f32_fp8(v, true);
            s0 += lo[0]; s1 += lo[1]; s2 += hi[0]; s3 += hi[1];
        }
    }

    const float w = 1.0f / fmaxf((float)(end - beg), 1.0f);
    const ushort4 bu = *(const ushort4*)(Ab + ((size_t)node << 7) + (lane << 2));
    const float h0 = fmaxf(b2f(bu.x) + s0 * w, 0.f);
    const float h1 = fmaxf(b2f(bu.y) + s1 * w, 0.f);
    const float h2 = fmaxf(b2f(bu.z) + s2 * w, 0.f);
    const float h3 = fmaxf(b2f(bu.w) + s3 * w, 0.f);

    const float4 wl = *(const float4*)(Wl + (lane << 2));
    const float4 wr = *(const float4*)(Wr + (lane << 2));
    float dl = h0 * wl.x + h1 * wl.y + h2 * wl.z + h3 * wl.w;
    float dr = h0 * wr.x + h1 * wr.y + h2 * wr.z + h3 * wr.w;
    #pragma unroll
    for (int off = 16; off > 0; off >>= 1) {
        dl += __shfl_down(dl, off, 64);
        dr += __shfl_down(dr, off, 64);
    }
    if (lane == 0) {
        t3[node] = dl;
        out[node] = dr + b[0];
    }
}

__global__ __launch_bounds__(256) void agg1(
    const int* __restrict__ endoff, const int* __restrict__ csr,
    const float* __restrict__ t3, float* __restrict__ out, int N, int E)
{
    const int i = blockIdx.x * blockDim.x + threadIdx.x;
    if (i >= N) return;
    const int beg = endoff[i];
    const int end = (i + 1 < N) ? endoff[i + 1] : E;
    int p = beg;
    float s = 0.f;
    for (; p + 4 <= end; p += 4)
        s += (t3[csr[p]] + t3[csr[p + 1]]) + (t3[csr[p + 2]] + t3[csr[p + 3]]);
    for (; p < end; ++p) s += t3[csr[p]];
    out[i] += s / fmaxf((float)(end - beg), 1.0f);
}

extern "C" void kernel_launch(void* const* d_in, const int* in_sizes, int n_in,
                              void* d_out, int out_size, void* d_ws, size_t ws_size,
                              hipStream_t stream) {
    const float* x   = (const float*)d_in[0];
    const int*   ei  = (const int*)d_in[1];
    const float* Wl1 = (const float*)d_in[2];
    const float* bl1 = (const float*)d_in[3];
    const float* Wr1 = (const float*)d_in[4];
    const float* Wl2 = (const float*)d_in[5];
    const float* bl2 = (const float*)d_in[6];
    const float* Wr2 = (const float*)d_in[7];
    const float* Wl3 = (const float*)d_in[8];
    const float* bl3 = (const float*)d_in[9];
    const float* Wr3 = (const float*)d_in[10];
    float* out = (float*)d_out;

    const int N = in_sizes[0] / 256;   // 100000
    const int E = in_sizes[1] / 2;     // 1600000
    const int* src = ei;
    const int* dst = ei + E;

    // ---- workspace layout, race-free aliasing ----------------------------
    //   prep:       W X1b[0,51.2), rank, deg
    //   L1+fill:    R X1b,rank,starts  W T1b(fp8)[51.2,76.8) A1b[102.4,153.6) csr
    //   agg256_b:   R T1b,A1b,csr      W X2b[0,51.2)          (X1b dead)
    //   gemm_l2:    R X2b              W T2b(fp8)[51.2,64.0) A2b[76.8,102.4)
    //   agg_gemv3:  R T2b,A2b,csr      W t3,out               (X2b dead)
    //   agg1:       R t3,csr           RW out
    char* W = (char*)d_ws;
    const size_t MB512 = (size_t)100000 * 512;   // 51.2MB
    unsigned short* X1b = (unsigned short*)(W);
    unsigned char*  T1b = (unsigned char*)(W + MB512);           // fp8, 25.6MB
    unsigned short* A1b = (unsigned short*)(W + 2 * MB512);
    unsigned short* X2b = (unsigned short*)(W);                  // over dead X1b
    unsigned char*  T2b = (unsigned char*)(W + MB512);           // fp8, over dead T1b
    unsigned short* A2b = (unsigned short*)(W + MB512 + MB512 / 2);
    char* S = W + 3 * MB512;                     // smalls @ 153.6M
    int*   endoff = (int*)(S);
    int*   bsums  = (int*)(S + (size_t)N * 4);
    float* t3     = (float*)(S + (size_t)N * 4 + 1024);
    int*   csr    = (int*)(S + (size_t)N * 8 + 1024);
    unsigned short* Wl1s = (unsigned short*)(S + (size_t)N * 8 + 1024 + (size_t)E * 4);
    unsigned short* Wr1s = Wl1s + 65536;
    unsigned short* Wl2s = Wr1s + 65536;
    unsigned short* Wr2s = Wl2s + 32768;
    unsigned short* rank = Wr2s + 32768;         // ushort[E], +3.2MB

    // ---- prep: fused conversions + interleaved degree count ----
    hipMemsetAsync(endoff, 0, (size_t)N * sizeof(int), stream);
    prep_fused<<<25768, 256, 0, stream>>>(
        x, X1b, Wl1, Wr1, Wl2, Wr2, Wl1s, Wr1s, Wl2s, Wr2s,
        dst, endoff, rank, E);
    const int nScanBlocks = (N + 1023) / 1024;
    scan_phaseA<<<nScanBlocks, 256, 0, stream>>>(endoff, bsums, N);
    scan_phaseB<<<1, 256, 0, stream>>>(bsums, nScanBlocks);
    scan_phaseC<<<nScanBlocks, 256, 0, stream>>>(endoff, bsums, N);

    // ---- Layer 1 GEMM (LDS-staged, fp8 T) fused with atomic-free fill ----
    gemm_l1_fill<<<3128 * 3, 256, 0, stream>>>(X1b, Wl1s, Wr1s, bl1, T1b, A1b, N,
                                               src, dst, endoff, rank, csr, E);

    // ---- Layer 2: gather (half-wave/node, fp8 rows) then GEMM ----
    agg256_b<<<(N * 32 + 255) / 256, 256, 0, stream>>>(endoff, csr, T1b, A1b, X2b, N, E);
    gemm_bf16<<<dim3(2, (N + 127) / 128), 256, 0, stream>>>(X2b, Wl2s, Wr2s, bl2,
                                                            T2b, A2b, N, 128);

    // ---- Layer 3: fused agg128 (fp8) + gemv, then final scalar agg ----
    agg_gemv3<<<(N * 32 + 255) / 256, 256, 0, stream>>>(endoff, csr, T2b, A2b,
                                                        Wl3, Wr3, bl3, t3, out, N, E);
    agg1<<<(N + 255) / 256, 256, 0, stream>>>(endoff, csr, t3, out, N, E);
}